// Round 6
// baseline (1794.103 us; speedup 1.0000x reference)
//
#include <hip/hip_runtime.h>
#include <hip/hip_fp16.h>

#define TLEN 8192
#define NTS  256
#define CLEN 32
#define NCH  256           // TLEN / CLEN
#define SLOT2 66048        // 256*128 bf16 (65536) + 128 f32 scales (512)

typedef __bf16 bf16x8 __attribute__((ext_vector_type(8)));
typedef float  f32x4  __attribute__((ext_vector_type(4)));
union U128 { uint4 u; bf16x8 v; };

__device__ __forceinline__ unsigned f2bfu(float x) {
    unsigned u = __float_as_uint(x);
    return (u + 0x7fffu + ((u >> 16) & 1u)) >> 16;
}
__device__ __forceinline__ unsigned pk2(float lo, float hi) {
    return f2bfu(lo) | (f2bfu(hi) << 16);
}
__device__ __forceinline__ float bf2f(unsigned short h) {
    return __uint_as_float(((unsigned)h) << 16);
}

// ===========================================================================
// Phase 1: block = chunk c (steps [32c, 32c+32)), 512 thr = 8 waves,
// wave w owns columns [32w, 32w+32). Per-thread acc = 128 f32 (no spill).
// Recurrence: C_new[j][r] = e_i[j] * sum_k QT[j][k] C[k][r], renormalized
// per column r each step (log-scale accumulated in rs).
// ===========================================================================
__global__ __launch_bounds__(512, 2) void crf_phase1(
        const float* __restrict__ emit, const float* __restrict__ trans,
        char* __restrict__ outX) {
    __shared__ alignas(16) char qt[131072];       // QT[j][k] bf16, swizzled
    __shared__ alignas(16) unsigned scr[8][512];  // 2 KiB exchange per wave
    __shared__ alignas(16) float eld[2][NTS];     // exp(emit row), dbuf

    const int t    = threadIdx.x;
    const int lane = t & 63;
    const int w    = t >> 6;              // 0..7
    const int gl   = lane >> 4;           // 0..3
    const int ln15 = lane & 15;
    const int c    = blockIdx.x;
    const int istart = (c == 0) ? 1 : CLEN * c;
    const int iend   = CLEN * c + CLEN;

    // ---- stage QT[j][k] = exp(trans[k][j]) as bf16, swizzled -------------
    {
        const int tt = t & 255;           // column j
        const int hlf = t >> 8;           // row-half
        for (int i0 = hlf * 128; i0 < hlf * 128 + 128; i0 += 8) {
            float v[8];
            #pragma unroll
            for (int ii = 0; ii < 8; ii++) v[ii] = __expf(trans[(i0 + ii) * NTS + tt]);
            uint4 u;
            u.x = pk2(v[0], v[1]); u.y = pk2(v[2], v[3]);
            u.z = pk2(v[4], v[5]); u.w = pk2(v[6], v[7]);
            *(uint4*)(qt + (((tt * 512) + i0 * 2) ^ ((tt & 7) << 4))) = u;
        }
    }
    if (t < NTS) eld[istart & 1][t] = __expf(emit[istart * NTS + t]);

    // ---- B := Identity columns, rs := 0 ----------------------------------
    bf16x8 Bf[8][2];
    #pragma unroll
    for (int kf = 0; kf < 8; kf++)
        #pragma unroll
        for (int cb = 0; cb < 2; cb++) {
            unsigned wd[4] = {0u, 0u, 0u, 0u};
            int r_glob = 32 * w + cb * 16 + ln15;
            int kbase = kf * 32 + gl * 8;
            #pragma unroll
            for (int e = 0; e < 8; e++)
                if (kbase + e == r_glob) wd[e >> 1] |= 0x3F80u << (16 * (e & 1));
            U128 q; q.u.x = wd[0]; q.u.y = wd[1]; q.u.z = wd[2]; q.u.w = wd[3];
            Bf[kf][cb] = q.v;
        }
    float rs[2] = {0.f, 0.f};
    __syncthreads();

    const int aswz = (lane & 7) << 4;
    for (int i = istart; i < iend; ++i) {
        float enext = 0.f;
        if (t < NTS && i + 1 < iend) enext = emit[(i + 1) * NTS + t];

        // ---- C = QT * B ---------------------------------------------------
        f32x4 Cacc[16][2];
        #pragma unroll
        for (int jb = 0; jb < 16; jb++)
            #pragma unroll
            for (int cb = 0; cb < 2; cb++) Cacc[jb][cb] = f32x4{0.f, 0.f, 0.f, 0.f};

        #pragma unroll
        for (int jb = 0; jb < 16; jb++) {
            const int abase = (jb * 16 + ln15) * 512 + gl * 16;
            #pragma unroll
            for (int kf = 0; kf < 8; kf++) {
                U128 a; a.u = *(const uint4*)(qt + ((abase + kf * 64) ^ aswz));
                #pragma unroll
                for (int cb = 0; cb < 2; cb++)
                    Cacc[jb][cb] = __builtin_amdgcn_mfma_f32_16x16x32_bf16(
                        a.v, Bf[kf][cb], Cacc[jb][cb], 0, 0, 0);
            }
        }

        // ---- scale rows j by exp(emit[i][j]) ------------------------------
        #pragma unroll
        for (int jb = 0; jb < 16; jb++) {
            float4 ev = *(const float4*)&eld[i & 1][jb * 16 + gl * 4];
            #pragma unroll
            for (int cb = 0; cb < 2; cb++) {
                Cacc[jb][cb][0] *= ev.x; Cacc[jb][cb][1] *= ev.y;
                Cacc[jb][cb][2] *= ev.z; Cacc[jb][cb][3] *= ev.w;
            }
        }
        // ---- per-column max + renormalize ---------------------------------
        float rn[2];
        #pragma unroll
        for (int cb = 0; cb < 2; cb++) {
            float m0 = Cacc[0][cb][0];
            #pragma unroll
            for (int jb = 0; jb < 16; jb++)
                #pragma unroll
                for (int rg = 0; rg < 4; rg++) m0 = fmaxf(m0, Cacc[jb][cb][rg]);
            m0 = fmaxf(m0, __shfl_xor(m0, 16));
            m0 = fmaxf(m0, __shfl_xor(m0, 32));
            rn[cb] = 1.0f / m0;
            rs[cb] += __logf(m0);
        }

        if (i == iend - 1) {
            // ---- write log-matrix + scales to half-slot 2c + (w>>2) --------
            char* SO = outX + (size_t)(2 * c + (w >> 2)) * SLOT2;
            #pragma unroll
            for (int jb = 0; jb < 16; jb++)
                #pragma unroll
                for (int cb = 0; cb < 2; cb++) {
                    int rsl = 32 * (w & 3) + cb * 16 + ln15;
                    #pragma unroll
                    for (int rg = 0; rg < 4; rg++) {
                        int j = jb * 16 + gl * 4 + rg;
                        float lv = __logf(Cacc[jb][cb][rg] * rn[cb]);
                        *(unsigned short*)(SO + ((j * 128 + rsl) << 1)) =
                            (unsigned short)f2bfu(lv);
                    }
                }
            if (lane < 16) {
                #pragma unroll
                for (int cb = 0; cb < 2; cb++) {
                    int rsl = 32 * (w & 3) + cb * 16 + lane;
                    *(float*)(SO + 65536 + rsl * 4) = rs[cb];
                }
            }
        } else {
            // ---- C -> next B via intra-wave LDS exchange -------------------
            #pragma unroll
            for (int kf = 0; kf < 8; kf++) {
                #pragma unroll
                for (int jbb = 0; jbb < 2; jbb++) {
                    const int jb = 2 * kf + jbb;
                    const int koct = 2 * jbb + (gl >> 1);
                    #pragma unroll
                    for (int cb = 0; cb < 2; cb++) {
                        const int addr = (koct * 512 + (cb * 16 + ln15) * 16
                                          + (gl & 1) * 8) ^ (koct << 4);
                        uint2 pk;
                        pk.x = pk2(Cacc[jb][cb][0] * rn[cb], Cacc[jb][cb][1] * rn[cb]);
                        pk.y = pk2(Cacc[jb][cb][2] * rn[cb], Cacc[jb][cb][3] * rn[cb]);
                        *(uint2*)((char*)&scr[w][0] + addr) = pk;
                    }
                }
                asm volatile("s_waitcnt lgkmcnt(0)" ::: "memory");
                __builtin_amdgcn_sched_barrier(0);
                #pragma unroll
                for (int cb = 0; cb < 2; cb++) {
                    const int rb = (gl * 512 + (cb * 16 + ln15) * 16) ^ (gl << 4);
                    U128 q; q.u = *(const uint4*)((const char*)&scr[w][0] + rb);
                    Bf[kf][cb] = q.v;
                }
                asm volatile("s_waitcnt lgkmcnt(0)" ::: "memory");
                __builtin_amdgcn_sched_barrier(0);
            }
            if (t < NTS) eld[(i + 1) & 1][t] = __expf(enext);
            __syncthreads();
        }
    }
}

// ===========================================================================
// Tree combine: output half-slot (pair p, half h) = Later(2p+1) x Earlier(2p)
// restricted to columns [128h, 128h+128). A = exp(S_Later + sL - sigma)
// staged to LDS; B-frags = exp(S_Earlier_h) from global via small LDS bounce.
// ===========================================================================
__global__ __launch_bounds__(256, 1) void crf_combine(
        const char* __restrict__ inb, char* __restrict__ outb) {
    __shared__ alignas(16) char qt[131072];
    __shared__ alignas(16) unsigned scr[4][512];
    __shared__ alignas(16) float sfac[NTS];
    __shared__ float smax[4];

    const int t = threadIdx.x;
    const int lane = t & 63;
    const int w = t >> 6;
    const int gl = lane >> 4;
    const int ln15 = lane & 15;
    const int p = blockIdx.x >> 1;
    const int h = blockIdx.x & 1;
    const char* SL0 = inb + (size_t)(4 * p + 2) * SLOT2;   // Later half 0
    const char* SL1 = inb + (size_t)(4 * p + 3) * SLOT2;   // Later half 1
    const char* SE  = inb + (size_t)(4 * p + h) * SLOT2;   // Earlier half h
    char* SO = outb + (size_t)(2 * p + h) * SLOT2;

    // sigma = max_k sL[k]
    float v = *(const float*)(((t < 128) ? SL0 : SL1) + 65536 + (t & 127) * 4);
    float m = v;
    #pragma unroll
    for (int off = 32; off; off >>= 1) m = fmaxf(m, __shfl_xor(m, off));
    if (lane == 0) smax[w] = m;
    __syncthreads();
    const float sigma = fmaxf(fmaxf(smax[0], smax[1]), fmaxf(smax[2], smax[3]));
    sfac[t] = v - sigma;
    __syncthreads();

    // ---- stage A = exp(S_Later[j][k] + sfac[k]) into swizzled qt ---------
    for (int it = 0; it < 32; it++) {
        int off = it * 2048 + t * 8;
        int j = off >> 8, k = off & 255;
        const char* src = (k < 128) ? (SL0 + (size_t)(j * 128 + k) * 2)
                                    : (SL1 + (size_t)(j * 128 + (k - 128)) * 2);
        uint4 d = *(const uint4*)src;
        float4 s0 = *(const float4*)&sfac[k];
        float4 s1 = *(const float4*)&sfac[k + 4];
        float sf[8] = {s0.x, s0.y, s0.z, s0.w, s1.x, s1.y, s1.z, s1.w};
        unsigned wds[4] = {d.x, d.y, d.z, d.w};
        unsigned outw[4];
        #pragma unroll
        for (int wi = 0; wi < 4; wi++) {
            float lo = __uint_as_float(wds[wi] << 16);
            float hi = __uint_as_float(wds[wi] & 0xffff0000u);
            outw[wi] = pk2(__expf(lo + sf[2 * wi]), __expf(hi + sf[2 * wi + 1]));
        }
        uint4 o; o.x = outw[0]; o.y = outw[1]; o.z = outw[2]; o.w = outw[3];
        *(uint4*)(qt + ((j * 512 + k * 2) ^ ((j & 7) << 4))) = o;
    }

    // ---- B frags = exp(S_E[k][r]) for this wave's 32 columns -------------
    bf16x8 Bf[8][2];
    #pragma unroll
    for (int kf = 0; kf < 8; kf++) {
        #pragma unroll
        for (int p2 = 0; p2 < 2; p2++) {
            int kk = p2 * 16 + (lane >> 2);
            uint4 d = *(const uint4*)(SE + (size_t)(32 * kf + kk) * 256
                                      + w * 64 + (lane & 3) * 16);
            *(uint4*)((char*)&scr[w][0] + kk * 64 + (lane & 3) * 16) = d;
        }
        asm volatile("s_waitcnt lgkmcnt(0)" ::: "memory");
        __builtin_amdgcn_sched_barrier(0);
        #pragma unroll
        for (int cb = 0; cb < 2; cb++) {
            unsigned wd[4] = {0u, 0u, 0u, 0u};
            #pragma unroll
            for (int e = 0; e < 8; e++) {
                int kloc = gl * 8 + e;
                unsigned short hh = *(const unsigned short*)
                    ((const char*)&scr[w][0] + kloc * 64 + (cb * 16 + ln15) * 2);
                float f = __expf(bf2f(hh));
                wd[e >> 1] |= f2bfu(f) << (16 * (e & 1));
            }
            U128 q; q.u.x = wd[0]; q.u.y = wd[1]; q.u.z = wd[2]; q.u.w = wd[3];
            Bf[kf][cb] = q.v;
        }
        asm volatile("s_waitcnt lgkmcnt(0)" ::: "memory");
        __builtin_amdgcn_sched_barrier(0);
    }
    __syncthreads();

    // ---- C = A * B -------------------------------------------------------
    f32x4 Cacc[16][2];
    #pragma unroll
    for (int jb = 0; jb < 16; jb++)
        #pragma unroll
        for (int cb = 0; cb < 2; cb++) Cacc[jb][cb] = f32x4{0.f, 0.f, 0.f, 0.f};
    const int aswz = (lane & 7) << 4;
    #pragma unroll
    for (int jb = 0; jb < 16; jb++) {
        const int abase = (jb * 16 + ln15) * 512 + gl * 16;
        #pragma unroll
        for (int kf = 0; kf < 8; kf++) {
            U128 a; a.u = *(const uint4*)(qt + ((abase + kf * 64) ^ aswz));
            #pragma unroll
            for (int cb = 0; cb < 2; cb++)
                Cacc[jb][cb] = __builtin_amdgcn_mfma_f32_16x16x32_bf16(
                    a.v, Bf[kf][cb], Cacc[jb][cb], 0, 0, 0);
        }
    }

    // ---- normalize per column, write out ---------------------------------
    float mx[2], rn[2];
    #pragma unroll
    for (int cb = 0; cb < 2; cb++) {
        float m0 = Cacc[0][cb][0];
        #pragma unroll
        for (int jb = 0; jb < 16; jb++)
            #pragma unroll
            for (int rg = 0; rg < 4; rg++) m0 = fmaxf(m0, Cacc[jb][cb][rg]);
        m0 = fmaxf(m0, __shfl_xor(m0, 16));
        m0 = fmaxf(m0, __shfl_xor(m0, 32));
        mx[cb] = m0; rn[cb] = 1.0f / m0;
    }
    #pragma unroll
    for (int jb = 0; jb < 16; jb++)
        #pragma unroll
        for (int cb = 0; cb < 2; cb++) {
            int rsl = w * 32 + cb * 16 + ln15;
            #pragma unroll
            for (int rg = 0; rg < 4; rg++) {
                int j = jb * 16 + gl * 4 + rg;
                float lv = __logf(Cacc[jb][cb][rg] * rn[cb]);
                *(unsigned short*)(SO + ((j * 128 + rsl) << 1)) =
                    (unsigned short)f2bfu(lv);
            }
        }
    if (lane < 16) {
        #pragma unroll
        for (int cb = 0; cb < 2; cb++) {
            int rsl = w * 32 + cb * 16 + lane;
            float se = *(const float*)(SE + 65536 + rsl * 4);
            *(float*)(SO + 65536 + rsl * 4) = se + sigma + __logf(mx[cb]);
        }
    }
}

// ===========================================================================
// Final: logZ = LSE_{j,r}( S[j][r] + s[r] + BOS[r] + emit[0][r] ),
// root matrix = half-slots 0,1 of `root`.
// ===========================================================================
__global__ __launch_bounds__(256) void crf_final(
        const char* __restrict__ root, const float* __restrict__ emit,
        const float* __restrict__ BOS, float* __restrict__ logZp) {
    __shared__ float rm[4], rsum[4];
    const int t = threadIdx.x, lane = t & 63, w = t >> 6;
    const char* slot = root + (size_t)(t >> 7) * SLOT2;
    const int rl = t & 127;
    const float base = *(const float*)(slot + 65536 + rl * 4) + BOS[t] + emit[t];
    float m = -INFINITY, s = 0.f;
    for (int j = 0; j < NTS; j++) {
        unsigned short hh = *(const unsigned short*)(slot + ((j * 128 + rl) << 1));
        float v = bf2f(hh) + base;
        float nm = fmaxf(m, v);
        s = s * __expf(m - nm) + __expf(v - nm);
        m = nm;
    }
    #pragma unroll
    for (int off = 32; off; off >>= 1) {
        float mo = __shfl_xor(m, off), so = __shfl_xor(s, off);
        float nm = fmaxf(m, mo);
        s = s * __expf(m - nm) + so * __expf(mo - nm);
        m = nm;
    }
    if (lane == 0) { rm[w] = m; rsum[w] = s; }
    __syncthreads();
    if (t == 0) {
        float M = fmaxf(fmaxf(rm[0], rm[1]), fmaxf(rm[2], rm[3]));
        float S = 0.f;
        #pragma unroll
        for (int k = 0; k < 4; k++) S += rsum[k] * __expf(rm[k] - M);
        logZp[0] = M + __logf(S);
    }
}

// ===========================================================================
// Fallback serial path (round-2, verified) + gold kernel
// ===========================================================================
__global__ __launch_bounds__(256) void crf_prep(const float* __restrict__ trans,
                                                __half2* __restrict__ Qp) {
    int j = threadIdx.x, p = blockIdx.x;
    float a = __expf(trans[(2 * p) * NTS + j]);
    float b = __expf(trans[(2 * p + 1) * NTS + j]);
    Qp[p * NTS + j] = __floats2half2_rn(a, b);
}

__global__ __launch_bounds__(512) void crf_forward(
        const float* __restrict__ emit, const float* __restrict__ BOS,
        const __half2* __restrict__ Qp_g, float* __restrict__ logZ_out) {
    __shared__ __half2 Qp[128 * NTS];
    __shared__ alignas(16) float w[NTS];
    __shared__ float part[2][NTS];
    __shared__ float ebuf[2][NTS];
    __shared__ float wavemax[8];
    const int t = threadIdx.x, j = t & 255, q = t >> 8, lane = t & 63, wv = t >> 6;
    for (int idx = t; idx < 128 * NTS; idx += 512) Qp[idx] = Qp_g[idx];
    float anew = -INFINITY;
    if (t < NTS) anew = BOS[t] + emit[t];
    float ml = anew;
    #pragma unroll
    for (int off = 32; off; off >>= 1) ml = fmaxf(ml, __shfl_down(ml, off));
    if (lane == 0) wavemax[wv] = ml;
    __syncthreads();
    float mstep = fmaxf(fmaxf(wavemax[0], wavemax[1]), fmaxf(wavemax[2], wavemax[3]));
    double Macc = (double)mstep;
    if (t < NTS) w[t] = __expf(anew - mstep);
    float epre = 0.f;
    if (q == 1) epre = emit[NTS + j];
    __syncthreads();
    for (int i = 1; i < TLEN; ++i) {
        if (q == 1) ebuf[i & 1][j] = epre;
        float acc = 0.f;
        const __half2* qptr = Qp + (q * 64) * NTS + j;
        const float2* wptr = (const float2*)(w + q * 128);
        #pragma unroll 16
        for (int kk = 0; kk < 64; ++kk) {
            __half2 qv = qptr[kk * NTS];
            float2 wv2 = wptr[kk];
            acc += __low2float(qv) * wv2.x + __high2float(qv) * wv2.y;
        }
        part[q][j] = acc;
        if (q == 1 && (i + 1) < TLEN) epre = emit[(i + 1) * NTS + j];
        __syncthreads();
        float an = 0.f;
        ml = -INFINITY;
        if (t < NTS) {
            float vv = part[0][t] + part[1][t];
            an = ebuf[i & 1][t] + __logf(vv);
            ml = an;
        }
        #pragma unroll
        for (int off = 32; off; off >>= 1) ml = fmaxf(ml, __shfl_down(ml, off));
        if (lane == 0 && wv < 4) wavemax[wv] = ml;
        __syncthreads();
        mstep = fmaxf(fmaxf(wavemax[0], wavemax[1]), fmaxf(wavemax[2], wavemax[3]));
        Macc += (double)mstep;
        if (t < NTS) w[t] = __expf(an - mstep);
        __syncthreads();
    }
    float s = (t < NTS) ? w[t] : 0.f;
    #pragma unroll
    for (int off = 32; off; off >>= 1) s += __shfl_down(s, off);
    if (lane == 0 && wv < 4) wavemax[wv] = s;
    __syncthreads();
    if (t == 0) {
        float tot = wavemax[0] + wavemax[1] + wavemax[2] + wavemax[3];
        logZ_out[0] = (float)(Macc + (double)__logf(tot));
    }
}

__global__ __launch_bounds__(512) void crf_gold(
        const float* __restrict__ emit, const int* __restrict__ y,
        const float* __restrict__ trans, const float* __restrict__ BOS,
        const float* __restrict__ EOS, const float* __restrict__ logZ_ws,
        float* __restrict__ out) {
    __shared__ float red[8];
    int t = threadIdx.x;
    float s = 0.f;
    for (int i = t; i < TLEN - 1; i += 512) {
        int yi = y[i], yn = y[i + 1];
        s += trans[yi * NTS + yn] + emit[i * NTS + yi];
    }
    #pragma unroll
    for (int off = 32; off; off >>= 1) s += __shfl_down(s, off);
    if ((t & 63) == 0) red[t >> 6] = s;
    __syncthreads();
    if (t == 0) {
        float tot = 0.f;
        #pragma unroll
        for (int k2 = 0; k2 < 8; ++k2) tot += red[k2];
        int y0 = y[0], yl = y[TLEN - 1];
        tot += BOS[y0] + EOS[yl] + emit[(TLEN - 1) * NTS + yl];
        out[0] = logZ_ws[0] - tot;
    }
}

// ===========================================================================
extern "C" void kernel_launch(void* const* d_in, const int* in_sizes, int n_in,
                              void* d_out, int out_size, void* d_ws, size_t ws_size,
                              hipStream_t stream) {
    const float* emit  = (const float*)d_in[0];
    const int*   y     = (const int*)d_in[1];
    const float* trans = (const float*)d_in[2];
    const float* BOS   = (const float*)d_in[3];
    const float* EOS   = (const float*)d_in[4];
    float* out = (float*)d_out;

    const size_t need = (size_t)(512 + 256) * SLOT2 + 256;
    if (ws_size >= need) {
        char* X = (char*)d_ws;                       // 512 half-slots
        char* Y = X + (size_t)512 * SLOT2;           // 256 half-slots
        float* logZ = (float*)(Y + (size_t)256 * SLOT2);

        crf_phase1<<<NCH, 512, 0, stream>>>(emit, trans, X);
        char* a = X; char* bb = Y;
        for (int n = NCH; n > 1; n >>= 1) {
            crf_combine<<<n, 256, 0, stream>>>(a, bb);
            char* tmp = a; a = bb; bb = tmp;
        }
        crf_final<<<1, 256, 0, stream>>>(a, emit, BOS, logZ);
        crf_gold<<<1, 512, 0, stream>>>(emit, y, trans, BOS, EOS, logZ, out);
    } else {
        __half2* Qp = (__half2*)d_ws;
        float* logZ = (float*)((char*)d_ws + 128 * NTS * sizeof(__half2));
        crf_prep<<<128, 256, 0, stream>>>(trans, Qp);
        crf_forward<<<1, 512, 0, stream>>>(emit, BOS, Qp, logZ);
        crf_gold<<<1, 512, 0, stream>>>(emit, y, trans, BOS, EOS, logZ, out);
    }
}

// Round 7
// 510.325 us; speedup vs baseline: 3.5156x; 3.5156x over previous
//
#include <hip/hip_runtime.h>
#include <hip/hip_fp16.h>

#define TLEN 8192
#define NTS  256
#define CLEN 32
#define NCH  256           // TLEN / CLEN
#define SLOT2 66048        // 256*128 bf16 (65536) + 128 f32 scales (512)

typedef __bf16 bf16x8 __attribute__((ext_vector_type(8)));
typedef float  f32x4  __attribute__((ext_vector_type(4)));
union U128 { uint4 u; bf16x8 v; };
union U64  { uint2 u; long l; };

__device__ __forceinline__ unsigned f2bfu(float x) {
    unsigned u = __float_as_uint(x);
    return (u + 0x7fffu + ((u >> 16) & 1u)) >> 16;
}
__device__ __forceinline__ unsigned pk2(float lo, float hi) {
    return f2bfu(lo) | (f2bfu(hi) << 16);
}
__device__ __forceinline__ float bf2f(unsigned short h) {
    return __uint_as_float(((unsigned)h) << 16);
}
// pack 4 f32 -> 4 bf8(e5m2) bytes in a u32
__device__ __forceinline__ unsigned pk4bf8(float a, float b, float c, float d) {
    int r = __builtin_amdgcn_cvt_pk_bf8_f32(a, b, 0, false);
    r = __builtin_amdgcn_cvt_pk_bf8_f32(c, d, r, true);
    return (unsigned)r;
}

// ===========================================================================
// Phase 1 (fp8): block = (chunk c, col-half h), 256 thr = 4 waves, wave owns
// 32 columns. Q kept in LDS as bf8 e5m2 (64 KiB) -> 2 blocks/CU.
// Recurrence: C_new[j][r] = e_i[j] * sum_k QT[j][k] C[k][r]; per-column
// renormalize each step; bf8 MFMA 16x16x32.
// ===========================================================================
__global__ __launch_bounds__(256, 2) void crf_phase1(
        const float* __restrict__ emit, const float* __restrict__ trans,
        char* __restrict__ outX) {
    __shared__ alignas(16) char qt8[65536];      // QT[j][k] bf8, granule-rotated
    __shared__ alignas(16) char scr[4][1280];    // exchange: 32 cols x 40 B/wave
    __shared__ alignas(16) float eld[2][NTS];    // exp(emit row), dbuf

    const int t    = threadIdx.x;
    const int lane = t & 63;
    const int w    = t >> 6;              // 0..3
    const int gl   = lane >> 4;           // 0..3
    const int ln15 = lane & 15;
    const int c    = blockIdx.x >> 1;
    const int h    = blockIdx.x & 1;
    const int istart = (c == 0) ? 1 : CLEN * c;
    const int iend   = CLEN * c + CLEN;

    // ---- stage QT[j][k] = exp(trans[k][j]) as bf8, rotated granules ------
    {
        const int ln = t & 15;
        for (int gk = 0; gk < 32; gk++) {
            float v[8];
            #pragma unroll
            for (int e = 0; e < 8; e++) v[e] = __expf(trans[(gk * 8 + e) * NTS + t]);
            uint2 u;
            u.x = pk4bf8(v[0], v[1], v[2], v[3]);
            u.y = pk4bf8(v[4], v[5], v[6], v[7]);
            const int p = (gk + 4 * ln + (ln >> 2)) & 31;
            *(uint2*)(qt8 + t * 256 + p * 8) = u;
        }
    }
    eld[istart & 1][t] = __expf(emit[istart * NTS + t]);

    // ---- precompute rotated A-read offsets per kf ------------------------
    int aoff[8];
    #pragma unroll
    for (int kf = 0; kf < 8; kf++) {
        const int p = (4 * kf + gl + 4 * ln15 + (ln15 >> 2)) & 31;
        aoff[kf] = ln15 * 256 + p * 8;
    }

    // ---- B := Identity columns (bf8 1.0 = 0x3C), rs := 0 -----------------
    uint2 Bf[8][2];
    #pragma unroll
    for (int kf = 0; kf < 8; kf++)
        #pragma unroll
        for (int cb = 0; cb < 2; cb++) {
            uint2 bu; bu.x = 0u; bu.y = 0u;
            const int r_glob = 128 * h + 32 * w + cb * 16 + ln15;
            if ((r_glob >> 3) == kf * 4 + gl) {
                const int e = r_glob & 7;
                if (e < 4) bu.x = 0x3Cu << (8 * e);
                else       bu.y = 0x3Cu << (8 * (e - 4));
            }
            Bf[kf][cb] = bu;
        }
    float rs[2] = {0.f, 0.f};
    __syncthreads();

    char* const mysc = &scr[w][0];
    for (int i = istart; i < iend; ++i) {
        float enext = 0.f;
        if (i + 1 < iend) enext = emit[(i + 1) * NTS + t];

        // ---- C = QT * B (bf8 MFMA) ---------------------------------------
        f32x4 Cacc[16][2];
        #pragma unroll
        for (int jb = 0; jb < 16; jb++)
            #pragma unroll
            for (int cb = 0; cb < 2; cb++) Cacc[jb][cb] = f32x4{0.f, 0.f, 0.f, 0.f};

        #pragma unroll
        for (int jb = 0; jb < 16; jb++) {
            #pragma unroll
            for (int kf = 0; kf < 8; kf++) {
                U64 a; a.u = *(const uint2*)(qt8 + (aoff[kf] + jb * 4096));
                #pragma unroll
                for (int cb = 0; cb < 2; cb++) {
                    U64 b; b.u = Bf[kf][cb];
                    Cacc[jb][cb] = __builtin_amdgcn_mfma_f32_16x16x32_bf8_bf8(
                        a.l, b.l, Cacc[jb][cb], 0, 0, 0);
                }
            }
        }

        // ---- scale rows j by exp(emit[i][j]) ------------------------------
        #pragma unroll
        for (int jb = 0; jb < 16; jb++) {
            float4 ev = *(const float4*)&eld[i & 1][jb * 16 + gl * 4];
            #pragma unroll
            for (int cb = 0; cb < 2; cb++) {
                Cacc[jb][cb][0] *= ev.x; Cacc[jb][cb][1] *= ev.y;
                Cacc[jb][cb][2] *= ev.z; Cacc[jb][cb][3] *= ev.w;
            }
        }
        // ---- per-column max + renormalize ---------------------------------
        float rn[2];
        #pragma unroll
        for (int cb = 0; cb < 2; cb++) {
            float m0 = Cacc[0][cb][0];
            #pragma unroll
            for (int jb = 0; jb < 16; jb++)
                #pragma unroll
                for (int rg = 0; rg < 4; rg++) m0 = fmaxf(m0, Cacc[jb][cb][rg]);
            m0 = fmaxf(m0, __shfl_xor(m0, 16));
            m0 = fmaxf(m0, __shfl_xor(m0, 32));
            rn[cb] = 1.0f / m0;
            rs[cb] += __logf(m0);
        }

        if (i == iend - 1) {
            // ---- write log-matrix + scales to half-slot 2c+h ---------------
            char* SO = outX + (size_t)(2 * c + h) * SLOT2;
            #pragma unroll
            for (int jb = 0; jb < 16; jb++)
                #pragma unroll
                for (int cb = 0; cb < 2; cb++) {
                    int rsl = w * 32 + cb * 16 + ln15;
                    #pragma unroll
                    for (int rg = 0; rg < 4; rg++) {
                        int j = jb * 16 + gl * 4 + rg;
                        float lv = __logf(Cacc[jb][cb][rg] * rn[cb]);
                        *(unsigned short*)(SO + ((j * 128 + rsl) << 1)) =
                            (unsigned short)f2bfu(lv);
                    }
                }
            if (lane < 16) {
                #pragma unroll
                for (int cb = 0; cb < 2; cb++) {
                    int rsl = w * 32 + cb * 16 + lane;
                    *(float*)(SO + 65536 + rsl * 4) = rs[cb];
                }
            }
        } else {
            // ---- C -> next B (bf8) via intra-wave LDS exchange -------------
            #pragma unroll
            for (int kf = 0; kf < 8; kf++) {
                #pragma unroll
                for (int jbb = 0; jbb < 2; jbb++) {
                    const int jb = 2 * kf + jbb;
                    #pragma unroll
                    for (int cb = 0; cb < 2; cb++) {
                        const int col = cb * 16 + ln15;
                        unsigned pk = pk4bf8(Cacc[jb][cb][0] * rn[cb],
                                             Cacc[jb][cb][1] * rn[cb],
                                             Cacc[jb][cb][2] * rn[cb],
                                             Cacc[jb][cb][3] * rn[cb]);
                        *(unsigned*)(mysc + col * 40 + jbb * 16 + gl * 4) = pk;
                    }
                }
                asm volatile("s_waitcnt lgkmcnt(0)" ::: "memory");
                __builtin_amdgcn_sched_barrier(0);
                #pragma unroll
                for (int cb = 0; cb < 2; cb++) {
                    const int col = cb * 16 + ln15;
                    Bf[kf][cb] = *(const uint2*)(mysc + col * 40 + gl * 8);
                }
                asm volatile("s_waitcnt lgkmcnt(0)" ::: "memory");
                __builtin_amdgcn_sched_barrier(0);
            }
            eld[(i + 1) & 1][t] = __expf(enext);
            __syncthreads();
        }
    }
}

// ===========================================================================
// Tree combine (bf16, unchanged): out half-slot (p,h) = Later(2p+1) x
// Earlier(2p), columns [128h,128h+128).
// ===========================================================================
__global__ __launch_bounds__(256, 1) void crf_combine(
        const char* __restrict__ inb, char* __restrict__ outb) {
    __shared__ alignas(16) char qt[131072];
    __shared__ alignas(16) unsigned scr[4][512];
    __shared__ alignas(16) float sfac[NTS];
    __shared__ float smax[4];

    const int t = threadIdx.x;
    const int lane = t & 63;
    const int w = t >> 6;
    const int gl = lane >> 4;
    const int ln15 = lane & 15;
    const int p = blockIdx.x >> 1;
    const int h = blockIdx.x & 1;
    const char* SL0 = inb + (size_t)(4 * p + 2) * SLOT2;
    const char* SL1 = inb + (size_t)(4 * p + 3) * SLOT2;
    const char* SE  = inb + (size_t)(4 * p + h) * SLOT2;
    char* SO = outb + (size_t)(2 * p + h) * SLOT2;

    float v = *(const float*)(((t < 128) ? SL0 : SL1) + 65536 + (t & 127) * 4);
    float m = v;
    #pragma unroll
    for (int off = 32; off; off >>= 1) m = fmaxf(m, __shfl_xor(m, off));
    if (lane == 0) smax[w] = m;
    __syncthreads();
    const float sigma = fmaxf(fmaxf(smax[0], smax[1]), fmaxf(smax[2], smax[3]));
    sfac[t] = v - sigma;
    __syncthreads();

    for (int it = 0; it < 32; it++) {
        int off = it * 2048 + t * 8;
        int j = off >> 8, k = off & 255;
        const char* src = (k < 128) ? (SL0 + (size_t)(j * 128 + k) * 2)
                                    : (SL1 + (size_t)(j * 128 + (k - 128)) * 2);
        uint4 d = *(const uint4*)src;
        float4 s0 = *(const float4*)&sfac[k];
        float4 s1 = *(const float4*)&sfac[k + 4];
        float sf[8] = {s0.x, s0.y, s0.z, s0.w, s1.x, s1.y, s1.z, s1.w};
        unsigned wds[4] = {d.x, d.y, d.z, d.w};
        unsigned outw[4];
        #pragma unroll
        for (int wi = 0; wi < 4; wi++) {
            float lo = __uint_as_float(wds[wi] << 16);
            float hi = __uint_as_float(wds[wi] & 0xffff0000u);
            outw[wi] = pk2(__expf(lo + sf[2 * wi]), __expf(hi + sf[2 * wi + 1]));
        }
        uint4 o; o.x = outw[0]; o.y = outw[1]; o.z = outw[2]; o.w = outw[3];
        *(uint4*)(qt + ((j * 512 + k * 2) ^ ((j & 7) << 4))) = o;
    }

    bf16x8 Bf[8][2];
    #pragma unroll
    for (int kf = 0; kf < 8; kf++) {
        #pragma unroll
        for (int p2 = 0; p2 < 2; p2++) {
            int kk = p2 * 16 + (lane >> 2);
            uint4 d = *(const uint4*)(SE + (size_t)(32 * kf + kk) * 256
                                      + w * 64 + (lane & 3) * 16);
            *(uint4*)((char*)&scr[w][0] + kk * 64 + (lane & 3) * 16) = d;
        }
        asm volatile("s_waitcnt lgkmcnt(0)" ::: "memory");
        __builtin_amdgcn_sched_barrier(0);
        #pragma unroll
        for (int cb = 0; cb < 2; cb++) {
            unsigned wd[4] = {0u, 0u, 0u, 0u};
            #pragma unroll
            for (int e = 0; e < 8; e++) {
                int kloc = gl * 8 + e;
                unsigned short hh = *(const unsigned short*)
                    ((const char*)&scr[w][0] + kloc * 64 + (cb * 16 + ln15) * 2);
                float f = __expf(bf2f(hh));
                wd[e >> 1] |= f2bfu(f) << (16 * (e & 1));
            }
            U128 q; q.u.x = wd[0]; q.u.y = wd[1]; q.u.z = wd[2]; q.u.w = wd[3];
            Bf[kf][cb] = q.v;
        }
        asm volatile("s_waitcnt lgkmcnt(0)" ::: "memory");
        __builtin_amdgcn_sched_barrier(0);
    }
    __syncthreads();

    f32x4 Cacc[16][2];
    #pragma unroll
    for (int jb = 0; jb < 16; jb++)
        #pragma unroll
        for (int cb = 0; cb < 2; cb++) Cacc[jb][cb] = f32x4{0.f, 0.f, 0.f, 0.f};
    const int aswz = (lane & 7) << 4;
    #pragma unroll
    for (int jb = 0; jb < 16; jb++) {
        const int abase = (jb * 16 + ln15) * 512 + gl * 16;
        #pragma unroll
        for (int kf = 0; kf < 8; kf++) {
            U128 a; a.u = *(const uint4*)(qt + ((abase + kf * 64) ^ aswz));
            #pragma unroll
            for (int cb = 0; cb < 2; cb++)
                Cacc[jb][cb] = __builtin_amdgcn_mfma_f32_16x16x32_bf16(
                    a.v, Bf[kf][cb], Cacc[jb][cb], 0, 0, 0);
        }
    }

    float mx[2], rn[2];
    #pragma unroll
    for (int cb = 0; cb < 2; cb++) {
        float m0 = Cacc[0][cb][0];
        #pragma unroll
        for (int jb = 0; jb < 16; jb++)
            #pragma unroll
            for (int rg = 0; rg < 4; rg++) m0 = fmaxf(m0, Cacc[jb][cb][rg]);
        m0 = fmaxf(m0, __shfl_xor(m0, 16));
        m0 = fmaxf(m0, __shfl_xor(m0, 32));
        mx[cb] = m0; rn[cb] = 1.0f / m0;
    }
    #pragma unroll
    for (int jb = 0; jb < 16; jb++)
        #pragma unroll
        for (int cb = 0; cb < 2; cb++) {
            int rsl = w * 32 + cb * 16 + ln15;
            #pragma unroll
            for (int rg = 0; rg < 4; rg++) {
                int j = jb * 16 + gl * 4 + rg;
                float lv = __logf(Cacc[jb][cb][rg] * rn[cb]);
                *(unsigned short*)(SO + ((j * 128 + rsl) << 1)) =
                    (unsigned short)f2bfu(lv);
            }
        }
    if (lane < 16) {
        #pragma unroll
        for (int cb = 0; cb < 2; cb++) {
            int rsl = w * 32 + cb * 16 + lane;
            float se = *(const float*)(SE + 65536 + rsl * 4);
            *(float*)(SO + 65536 + rsl * 4) = se + sigma + __logf(mx[cb]);
        }
    }
}

// ===========================================================================
// Final: logZ = LSE_{j,r}( S[j][r] + s[r] + BOS[r] + emit[0][r] )
// ===========================================================================
__global__ __launch_bounds__(256) void crf_final(
        const char* __restrict__ root, const float* __restrict__ emit,
        const float* __restrict__ BOS, float* __restrict__ logZp) {
    __shared__ float rm[4], rsum[4];
    const int t = threadIdx.x, lane = t & 63, w = t >> 6;
    const char* slot = root + (size_t)(t >> 7) * SLOT2;
    const int rl = t & 127;
    const float base = *(const float*)(slot + 65536 + rl * 4) + BOS[t] + emit[t];
    float m = -INFINITY, s = 0.f;
    for (int j = 0; j < NTS; j++) {
        unsigned short hh = *(const unsigned short*)(slot + ((j * 128 + rl) << 1));
        float v = bf2f(hh) + base;
        float nm = fmaxf(m, v);
        s = s * __expf(m - nm) + __expf(v - nm);
        m = nm;
    }
    #pragma unroll
    for (int off = 32; off; off >>= 1) {
        float mo = __shfl_xor(m, off), so = __shfl_xor(s, off);
        float nm = fmaxf(m, mo);
        s = s * __expf(m - nm) + so * __expf(mo - nm);
        m = nm;
    }
    if (lane == 0) { rm[w] = m; rsum[w] = s; }
    __syncthreads();
    if (t == 0) {
        float M = fmaxf(fmaxf(rm[0], rm[1]), fmaxf(rm[2], rm[3]));
        float S = 0.f;
        #pragma unroll
        for (int k = 0; k < 4; k++) S += rsum[k] * __expf(rm[k] - M);
        logZp[0] = M + __logf(S);
    }
}

// ===========================================================================
// Fallback serial path + gold kernel (unchanged, verified)
// ===========================================================================
__global__ __launch_bounds__(256) void crf_prep(const float* __restrict__ trans,
                                                __half2* __restrict__ Qp) {
    int j = threadIdx.x, p = blockIdx.x;
    float a = __expf(trans[(2 * p) * NTS + j]);
    float b = __expf(trans[(2 * p + 1) * NTS + j]);
    Qp[p * NTS + j] = __floats2half2_rn(a, b);
}

__global__ __launch_bounds__(512) void crf_forward(
        const float* __restrict__ emit, const float* __restrict__ BOS,
        const __half2* __restrict__ Qp_g, float* __restrict__ logZ_out) {
    __shared__ __half2 Qp[128 * NTS];
    __shared__ alignas(16) float w[NTS];
    __shared__ float part[2][NTS];
    __shared__ float ebuf[2][NTS];
    __shared__ float wavemax[8];
    const int t = threadIdx.x, j = t & 255, q = t >> 8, lane = t & 63, wv = t >> 6;
    for (int idx = t; idx < 128 * NTS; idx += 512) Qp[idx] = Qp_g[idx];
    float anew = -INFINITY;
    if (t < NTS) anew = BOS[t] + emit[t];
    float ml = anew;
    #pragma unroll
    for (int off = 32; off; off >>= 1) ml = fmaxf(ml, __shfl_down(ml, off));
    if (lane == 0) wavemax[wv] = ml;
    __syncthreads();
    float mstep = fmaxf(fmaxf(wavemax[0], wavemax[1]), fmaxf(wavemax[2], wavemax[3]));
    double Macc = (double)mstep;
    if (t < NTS) w[t] = __expf(anew - mstep);
    float epre = 0.f;
    if (q == 1) epre = emit[NTS + j];
    __syncthreads();
    for (int i = 1; i < TLEN; ++i) {
        if (q == 1) ebuf[i & 1][j] = epre;
        float acc = 0.f;
        const __half2* qptr = Qp + (q * 64) * NTS + j;
        const float2* wptr = (const float2*)(w + q * 128);
        #pragma unroll 16
        for (int kk = 0; kk < 64; ++kk) {
            __half2 qv = qptr[kk * NTS];
            float2 wv2 = wptr[kk];
            acc += __low2float(qv) * wv2.x + __high2float(qv) * wv2.y;
        }
        part[q][j] = acc;
        if (q == 1 && (i + 1) < TLEN) epre = emit[(i + 1) * NTS + j];
        __syncthreads();
        float an = 0.f;
        ml = -INFINITY;
        if (t < NTS) {
            float vv = part[0][t] + part[1][t];
            an = ebuf[i & 1][t] + __logf(vv);
            ml = an;
        }
        #pragma unroll
        for (int off = 32; off; off >>= 1) ml = fmaxf(ml, __shfl_down(ml, off));
        if (lane == 0 && wv < 4) wavemax[wv] = ml;
        __syncthreads();
        mstep = fmaxf(fmaxf(wavemax[0], wavemax[1]), fmaxf(wavemax[2], wavemax[3]));
        Macc += (double)mstep;
        if (t < NTS) w[t] = __expf(an - mstep);
        __syncthreads();
    }
    float s = (t < NTS) ? w[t] : 0.f;
    #pragma unroll
    for (int off = 32; off; off >>= 1) s += __shfl_down(s, off);
    if (lane == 0 && wv < 4) wavemax[wv] = s;
    __syncthreads();
    if (t == 0) {
        float tot = wavemax[0] + wavemax[1] + wavemax[2] + wavemax[3];
        logZ_out[0] = (float)(Macc + (double)__logf(tot));
    }
}

__global__ __launch_bounds__(512) void crf_gold(
        const float* __restrict__ emit, const int* __restrict__ y,
        const float* __restrict__ trans, const float* __restrict__ BOS,
        const float* __restrict__ EOS, const float* __restrict__ logZ_ws,
        float* __restrict__ out) {
    __shared__ float red[8];
    int t = threadIdx.x;
    float s = 0.f;
    for (int i = t; i < TLEN - 1; i += 512) {
        int yi = y[i], yn = y[i + 1];
        s += trans[yi * NTS + yn] + emit[i * NTS + yi];
    }
    #pragma unroll
    for (int off = 32; off; off >>= 1) s += __shfl_down(s, off);
    if ((t & 63) == 0) red[t >> 6] = s;
    __syncthreads();
    if (t == 0) {
        float tot = 0.f;
        #pragma unroll
        for (int k2 = 0; k2 < 8; ++k2) tot += red[k2];
        int y0 = y[0], yl = y[TLEN - 1];
        tot += BOS[y0] + EOS[yl] + emit[(TLEN - 1) * NTS + yl];
        out[0] = logZ_ws[0] - tot;
    }
}

// ===========================================================================
extern "C" void kernel_launch(void* const* d_in, const int* in_sizes, int n_in,
                              void* d_out, int out_size, void* d_ws, size_t ws_size,
                              hipStream_t stream) {
    const float* emit  = (const float*)d_in[0];
    const int*   y     = (const int*)d_in[1];
    const float* trans = (const float*)d_in[2];
    const float* BOS   = (const float*)d_in[3];
    const float* EOS   = (const float*)d_in[4];
    float* out = (float*)d_out;

    const size_t need = (size_t)(512 + 256) * SLOT2 + 256;
    if (ws_size >= need) {
        char* X = (char*)d_ws;                       // 512 half-slots
        char* Y = X + (size_t)512 * SLOT2;           // 256 half-slots
        float* logZ = (float*)(Y + (size_t)256 * SLOT2);

        crf_phase1<<<2 * NCH, 256, 0, stream>>>(emit, trans, X);
        char* a = X; char* bb = Y;
        for (int n = NCH; n > 1; n >>= 1) {
            crf_combine<<<n, 256, 0, stream>>>(a, bb);
            char* tmp = a; a = bb; bb = tmp;
        }
        crf_final<<<1, 256, 0, stream>>>(a, emit, BOS, logZ);
        crf_gold<<<1, 512, 0, stream>>>(emit, y, trans, BOS, EOS, logZ, out);
    } else {
        __half2* Qp = (__half2*)d_ws;
        float* logZ = (float*)((char*)d_ws + 128 * NTS * sizeof(__half2));
        crf_prep<<<128, 256, 0, stream>>>(trans, Qp);
        crf_forward<<<1, 512, 0, stream>>>(emit, BOS, Qp, logZ);
        crf_gold<<<1, 512, 0, stream>>>(emit, y, trans, BOS, EOS, logZ, out);
    }
}